// Round 1
// baseline (105.778 us; speedup 1.0000x reference)
//
#include <hip/hip_runtime.h>
#include <hip/hip_bf16.h>
#include <math.h>

#define BS   8
#define NPTS 2048
#define CCH  12      // channels per flow
#define NF   2       // flow dim
#define DIM  24      // NF*CCH, feats order: d = f*12 + c
#define KPAD 32      // MFMA K (24 + 8 zero pad)
#define KTOP 16
#define NWV  8       // waves per fused block (512 threads)
#define RPB  16      // rows per block (one m-tile)
#define CBUF 112     // survivor slots per row (~32 expected, +9.5 sigma)
#define CBS  113     // padded stride
#define WVS  20      // padded row stride of per-wave C tile (16B-aligned)

#define NROWS    (BS * NPTS)
#define TGT_BASE (NROWS * KTOP * CCH)   // 3145728

typedef unsigned long long u64;
typedef unsigned int       u32;
typedef unsigned short     u16;
typedef __attribute__((ext_vector_type(8))) short short8;   // bf16x8 MFMA frag
typedef __attribute__((ext_vector_type(4))) float f32x4;

// ws layout (bytes)
#define WS_FEATS 0                                  // fp32 [NROWS][24]
#define WS_RAW   (NROWS * DIM * 4)                  // fp32 [NROWS][12]
#define WS_FHI   (WS_RAW + NROWS * CCH * 4)         // bf16 [NROWS][32]
#define WS_FLO   (WS_FHI + NROWS * KPAD * 2)        // bf16 [NROWS][32]

// Emulate np.linalg.norm(v) + 1e-8 in float32 exactly (numpy pairwise sum, n=24)
__device__ __forceinline__ float np_norm_den(const float* __restrict__ v)
{
#pragma clang fp contract(off)
    float s[DIM];
    #pragma unroll
    for (int d = 0; d < DIM; ++d) s[d] = v[d] * v[d];
    float r[8];
    #pragma unroll
    for (int j = 0; j < 8; ++j) r[j] = (s[j] + s[j + 8]) + s[j + 16];
    float res = ((r[0] + r[1]) + (r[2] + r[3])) + ((r[4] + r[5]) + (r[6] + r[7]));
    return sqrtf(res) + 1e-8f;
}

// Monotone float -> u32 (preserves total order for finite floats)
__device__ __forceinline__ u32 ordf(float f)
{
    u32 u = __float_as_uint(f);
    return ((int)u >= 0) ? (u | 0x80000000u) : ~u;
}

// round-to-nearest-even fp32 -> bf16 bits (finite inputs)
__device__ __forceinline__ u16 bf16_rne(float x)
{
    u32 bits = __float_as_uint(x);
    bits += 0x7fffu + ((bits >> 16) & 1u);
    return (u16)(bits >> 16);
}

// ---------------------------------------------------------------------------
// Kernel 0: normalize rows (numpy-exact fp32); write fp32 feats, bf16 hi/lo
// (K-padded to 32), raw flow slice, and the tgt_out output.
// R14: 256 blocks x 64 thr (was 64x256) -> covers 256 CUs instead of 64.
// Latency-bound kernel (no TLP within a block), so 4x CU coverage ~= 4x faster.
// ---------------------------------------------------------------------------
__global__ __launch_bounds__(64) void prep_kernel(
    const float* __restrict__ x_c,     // [8][12][2][2048]
    const int*   __restrict__ flow_p,
    float*       __restrict__ feats,   // [NROWS][24] normalized fp32
    u16*         __restrict__ fhi,     // [NROWS][32] bf16 hi
    u16*         __restrict__ flo,     // [NROWS][32] bf16 lo
    float*       __restrict__ raw,     // [NROWS][12] raw flow slice
    float*       __restrict__ out)
{
    const int t = blockIdx.x * 64 + threadIdx.x;   // global row
    const int b = t >> 11;
    const int n = t & (NPTS - 1);
    const float* xb = x_c + (size_t)b * CCH * NF * NPTS;

    float v[DIM];
    float fn[DIM];
    {
#pragma clang fp contract(off)
        #pragma unroll
        for (int c = 0; c < CCH; ++c)
            #pragma unroll
            for (int f = 0; f < NF; ++f)
                v[f * CCH + c] = xb[(c * NF + f) * NPTS + n];

        const float den = np_norm_den(v);
        float* fo = feats + (size_t)t * DIM;
        #pragma unroll
        for (int d = 0; d < DIM; ++d) { fn[d] = v[d] / den; fo[d] = fn[d]; }
    }

    u16* ho = fhi + (size_t)t * KPAD;
    u16* lo = flo + (size_t)t * KPAD;
    #pragma unroll
    for (int d = 0; d < DIM; ++d) {
        const u16 hb = bf16_rne(fn[d]);
        const float hf = __uint_as_float((u32)hb << 16);
        ho[d] = hb;
        lo[d] = bf16_rne(fn[d] - hf);
    }
    #pragma unroll
    for (int d = DIM; d < KPAD; ++d) { ho[d] = 0; lo[d] = 0; }

    const int flow = flow_p[0];
    float* ro = raw + (size_t)t * CCH;
    #pragma unroll
    for (int c = 0; c < CCH; ++c) {
        const float xv = flow ? v[CCH + c] : v[c];
        ro[c] = xv;
        out[TGT_BASE + ((size_t)b * CCH + c) * NPTS + n] = xv;
    }
}

// 4-stage bitonic cleanup, desc (list must be bitonic)
#define CLEANUP_DESC(arr)                                         \
    _Pragma("unroll")                                             \
    for (int j_ = 8; j_ > 0; j_ >>= 1)                            \
        _Pragma("unroll")                                         \
        for (int i_ = 0; i_ < KTOP; ++i_) {                       \
            const int l_ = i_ | j_;                               \
            if (l_ > i_) {                                        \
                const float a_ = arr[i_], c_ = arr[l_];           \
                arr[i_] = fmaxf(a_, c_);                          \
                arr[l_] = fminf(a_, c_);                          \
            }                                                     \
        }

// Split-bf16 approx dot tile: two independent MFMA chains (acc: hi*hi -> lo*hi,
// acc2: hi*lo) + one f32x4 add.  R14: was a 3-deep dependent chain; the extra
// rounding (~6e-8) is negligible vs the 8e-4 threshold margin, and the final
// output is index-driven via the bit-exact rescue, so results are unchanged.
#define APPROX_TILE(ACC, AHI, ALO, BHI, BLO)                                  \
    f32x4 ACC  = {0.0f, 0.0f, 0.0f, 0.0f};                                    \
    {                                                                         \
        f32x4 acc2_ = {0.0f, 0.0f, 0.0f, 0.0f};                               \
        ACC   = __builtin_amdgcn_mfma_f32_16x16x32_bf16(AHI, BHI, ACC, 0,0,0);\
        acc2_ = __builtin_amdgcn_mfma_f32_16x16x32_bf16(AHI, BLO, acc2_,0,0,0);\
        ACC   = __builtin_amdgcn_mfma_f32_16x16x32_bf16(ALO, BHI, ACC, 0,0,0);\
        _Pragma("unroll")                                                     \
        for (int i_ = 0; i_ < 4; ++i_) ACC[i_] += acc2_[i_];                  \
    }

// ---------------------------------------------------------------------------
// Fused kernel: block = (b, 16-row chunk), 512 thr = 8 waves.
// R14: __launch_bounds__(512, 6) — cap VGPR at ~80-85 so 3 blocks/CU fit
// (6 waves/SIMD instead of 4).  Theory: kernel is latency-stalled (static
// issue ~10 µs vs ~40 µs measured); +50% TLP attacks the stall factor.
// MFMA split-bf16 approx dots (|approx-exact| <= eps ~1.3e-4).
// Pass 1 (subset, first 1024 cands): wave w scans [w*128,+128) in 2 rounds of
// 4 tiles; per-lane (row=p, cand-quad=q) collects 16 values/round via a tiny
// per-wave LDS transpose, sort16+merge into per-lane top-16; shfl_xor(16,32)
// pairwise merges unify the 4 row-copies; 3-round LDS tournament over 8
// waves -> lb; thr = lb - 8e-4 (same margin proof as R13).
// Pass 2: all 2048 cands, compare in C-frag registers, sparse append.
// Exact rescue (bit-exact fp32 chain) + parallel rank-select + gather.
// ---------------------------------------------------------------------------
__global__ __launch_bounds__(512, 6) void fused_topk_kernel(
    const float* __restrict__ feats,
    const u16*   __restrict__ fhi,
    const u16*   __restrict__ flo,
    const float* __restrict__ raw,
    float*       __restrict__ out)
{
    __shared__ union {
        float wval[NWV * 16 * WVS];   // 10 KiB: per-wave C tiles [w][cand16][row WVS]
        float vk[NWV * KTOP * 16];    // 8 KiB: tournament lists [w][k][row16]
        u64   ckey[RPB * CBS];        // 14.1 KiB: survivors (aliases, disjoint in time)
    } sh;
    __shared__ float thr_s[RPB];
    __shared__ int   cnt[RPB];
    __shared__ int   sel[RPB][KTOP];

    const int tid  = threadIdx.x;
    const int lane = tid & 63;
    const int w    = __builtin_amdgcn_readfirstlane(tid >> 6);  // 0..7
    const int b     = blockIdx.x >> 7;
    const int chunk = blockIdx.x & 127;
    const int rb    = chunk * RPB;           // row base within batch
    const int p     = lane & 15;             // A-row / C-col index
    const int q     = lane >> 4;             // quad

    if (tid < RPB) cnt[tid] = 0;

    // A fragments: 16 rows (one m-tile), hi/lo
    short8 ahi, alo;
    {
        const size_t ae = ((size_t)(b * NPTS + rb + p)) * KPAD + q * 8;
        ahi = *(const short8*)(fhi + ae);
        alo = *(const short8*)(flo + ae);
    }

    float* wv = sh.wval + w * (16 * WVS);    // private C tile [cand][row]

    float vlist[KTOP];
    #pragma unroll
    for (int k = 0; k < KTOP; ++k) vlist[k] = -3.0f;

    // ---- Pass 1 (subset: wave w scans [w*128, +128) in 2 rounds x 4 tiles) ----
    for (int ro = 0; ro < 2; ++ro) {
        float bv[16];
        #pragma unroll
        for (int t = 0; t < 4; ++t) {
            const int cb0 = w * 128 + ro * 64 + t * 16;
            const size_t be = ((size_t)(b * NPTS + cb0 + p)) * KPAD + q * 8;
            const short8 bhi = *(const short8*)(fhi + be);
            const short8 blo = *(const short8*)(flo + be);
            APPROX_TILE(acc, ahi, alo, bhi, blo)
            // lane holds cand p, rows q*4+i  ->  store [cand][row]
            *(f32x4*)(wv + p * WVS + q * 4) = acc;
            // read back: this lane takes row p, cands q*4+i (values only)
            #pragma unroll
            for (int i = 0; i < 4; ++i)
                bv[t * 4 + i] = wv[(q * 4 + i) * WVS + p];
        }
        // bitonic sort 16 ASC
        #pragma unroll
        for (int k = 2; k <= 16; k <<= 1)
            #pragma unroll
            for (int j = k >> 1; j > 0; j >>= 1)
                #pragma unroll
                for (int i = 0; i < 16; ++i) {
                    const int l = i | j;
                    if (l > i) {
                        const float a = bv[i], c = bv[l];
                        if ((i & k) == 0) { bv[i] = fminf(a, c); bv[l] = fmaxf(a, c); }
                        else              { bv[i] = fmaxf(a, c); bv[l] = fminf(a, c); }
                    }
                }
        // merge (vlist desc + bv asc -> bitonic), cleanup desc
        #pragma unroll
        for (int i = 0; i < 16; ++i) vlist[i] = fmaxf(vlist[i], bv[i]);
        CLEANUP_DESC(vlist)
    }

    // ---- intra-wave merges: unify the 4 row-copies (g-quads) ----
    #pragma unroll
    for (int x = 16; x <= 32; x <<= 1) {
        float other[KTOP];
        #pragma unroll
        for (int k = 0; k < KTOP; ++k) other[k] = __shfl_xor(vlist[k], x);
        #pragma unroll
        for (int i = 0; i < KTOP; ++i)
            vlist[i] = fmaxf(vlist[i], other[KTOP - 1 - i]);
        CLEANUP_DESC(vlist)
    }

    __syncthreads();   // pass-1 tiles dead; alias as vk

    // ---- tournament over 8 waves: 3 rounds ----
    for (int half = NWV / 2; half >= 1; half >>= 1) {
        if (w >= half && w < 2 * half && q == 0) {
            #pragma unroll
            for (int k = 0; k < KTOP; ++k)
                sh.vk[(w * KTOP + k) * 16 + p] = vlist[k];
        }
        __syncthreads();
        if (w < half) {
            float other[KTOP];
            #pragma unroll
            for (int k = 0; k < KTOP; ++k)
                other[k] = sh.vk[((w + half) * KTOP + k) * 16 + p];
            #pragma unroll
            for (int i = 0; i < KTOP; ++i)
                vlist[i] = fmaxf(vlist[i], other[KTOP - 1 - i]);
            CLEANUP_DESC(vlist)
        }
        __syncthreads();
    }
    if (w == 0 && q == 0) thr_s[p] = vlist[KTOP - 1] - 8e-4f;   // lb - margin
    __syncthreads();                          // thr ready; vk dead -> ckey usable

    // per-position thresholds for this lane's C-fragment rows (q*4+i)
    float thrv[4];
    #pragma unroll
    for (int i = 0; i < 4; ++i) thrv[i] = thr_s[q * 4 + i];

    // ---- Pass 2: all 2048 cands (wave w: [w*256,+256)), register compare ----
    {
        size_t be_n = ((size_t)(b * NPTS + w * 256 + p)) * KPAD + q * 8;
        short8 nbhi = *(const short8*)(fhi + be_n);
        short8 nblo = *(const short8*)(flo + be_n);
        for (int t = 0; t < 16; ++t) {
            const int cb0 = w * 256 + t * 16;
            const short8 bhi = nbhi, blo = nblo;
            if (t < 15) {                         // prefetch next tile
                const size_t be = ((size_t)(b * NPTS + cb0 + 16 + p)) * KPAD + q * 8;
                nbhi = *(const short8*)(fhi + be);
                nblo = *(const short8*)(flo + be);
            }
            APPROX_TILE(acc, ahi, alo, bhi, blo)
            #pragma unroll
            for (int i = 0; i < 4; ++i) {
                if (acc[i] >= thrv[i]) {
                    const int r = q * 4 + i;            // row within chunk
                    const int pos = atomicAdd(&cnt[r], 1);
                    if (pos < CBUF)
                        sh.ckey[r * CBS + pos] = (u64)(u32)(cb0 + p);
                }
            }
        }
    }
    __syncthreads();

    // ---- exact rescue: bit-exact fp32 chain on survivors only ----
    {
        const int r = tid & 15;                  // row within chunk
        const float* fr = feats + (size_t)(b * NPTS + rb + r) * DIM;
        float rfn[DIM];
        #pragma unroll
        for (int d = 0; d < DIM; ++d) rfn[d] = fr[d];
        const int e = (cnt[r] < CBUF) ? cnt[r] : CBUF;
        for (int pos = tid >> 4; pos < e; pos += 32) {
            const int idx = (int)(u32)sh.ckey[r * CBS + pos];
            const float* cp = feats + (size_t)(b * NPTS + idx) * DIM;
            float acc = 0.0f;
            #pragma unroll
            for (int d = 0; d < DIM; ++d)
                acc = __builtin_fmaf(cp[d], rfn[d], acc);   // exact chain
            sh.ckey[r * CBS + pos] = ((u64)ordf(acc) << 32) | (u32)(2047 - idx);
        }
    }
    __syncthreads();

    // ---- parallel rank-select: 32 threads per row ----
    {
        const int L = tid >> 5;                  // 0..15
        const int g = tid & 31;
        const int e = (cnt[L] < CBUF) ? cnt[L] : CBUF;
        const u64* rowbuf = &sh.ckey[L * CBS];
        for (int pos = g; pos < e; pos += 32) {
            const u64 key = rowbuf[pos];
            int rank = 0;
            for (int p2 = 0; p2 < e; ++p2) rank += (rowbuf[p2] > key);
            if (rank < KTOP) sel[L][rank] = 2047 - (int)(key & 0xFFFFFFFFull);
        }
    }
    __syncthreads();

    // ---- gather: sx_c[b, n, k, c] = raw[(b*2048 + sel)*12 + c] ----
    const int rg = b * NPTS + rb;
    for (int e2 = tid; e2 < RPB * KTOP * CCH; e2 += 512) {
        const int L = e2 / (KTOP * CCH);
        const int r = e2 % (KTOP * CCH);
        const int k = r / CCH;
        const int c = r % CCH;
        out[((size_t)(rg + L) * KTOP + k) * CCH + c] =
            raw[((size_t)b * NPTS + sel[L][k]) * CCH + c];
    }
}

// ---------------------------------------------------------------------------
extern "C" void kernel_launch(void* const* d_in, const int* in_sizes, int n_in,
                              void* d_out, int out_size, void* d_ws, size_t ws_size,
                              hipStream_t stream)
{
    const float* x_c    = (const float*)d_in[0];
    const int*   flow_p = (const int*)d_in[1];
    float*       out    = (float*)d_out;

    float* feats = (float*)((char*)d_ws + WS_FEATS);
    float* raw   = (float*)((char*)d_ws + WS_RAW);
    u16*   fhi   = (u16*)  ((char*)d_ws + WS_FHI);
    u16*   flo   = (u16*)  ((char*)d_ws + WS_FLO);

    prep_kernel<<<NROWS / 64, 64, 0, stream>>>(x_c, flow_p, feats, fhi, flo, raw, out);
    fused_topk_kernel<<<BS * 128, 512, 0, stream>>>(feats, fhi, flo, raw, out);
}

// Round 2
// 103.922 us; speedup vs baseline: 1.0179x; 1.0179x over previous
//
#include <hip/hip_runtime.h>
#include <hip/hip_bf16.h>
#include <math.h>

#define BS   8
#define NPTS 2048
#define CCH  12      // channels per flow
#define NF   2       // flow dim
#define DIM  24      // NF*CCH, feats order: d = f*12 + c
#define KPAD 32      // MFMA K (24 + 8 zero pad)
#define KTOP 16
#define NWV  8       // waves per fused block (512 threads)
#define RPB  16      // rows per block (one m-tile)
#define CBUF 112     // survivor slots per row (~32 expected, +9.5 sigma)
#define CBS  113     // padded stride
#define WVS  20      // padded row stride of per-wave C tile (16B-aligned)

#define NROWS    (BS * NPTS)
#define TGT_BASE (NROWS * KTOP * CCH)   // 3145728

typedef unsigned long long u64;
typedef unsigned int       u32;
typedef unsigned short     u16;
typedef __attribute__((ext_vector_type(8))) short short8;   // bf16x8 MFMA frag
typedef __attribute__((ext_vector_type(4))) float f32x4;

// ws layout (bytes)
#define WS_FEATS 0                                  // fp32 [NROWS][24]
#define WS_RAW   (NROWS * DIM * 4)                  // fp32 [NROWS][12]
#define WS_FHI   (WS_RAW + NROWS * CCH * 4)         // bf16 [NROWS][32]
#define WS_FLO   (WS_FHI + NROWS * KPAD * 2)        // bf16 [NROWS][32]

// Emulate np.linalg.norm(v) + 1e-8 in float32 exactly (numpy pairwise sum, n=24)
__device__ __forceinline__ float np_norm_den(const float* __restrict__ v)
{
#pragma clang fp contract(off)
    float s[DIM];
    #pragma unroll
    for (int d = 0; d < DIM; ++d) s[d] = v[d] * v[d];
    float r[8];
    #pragma unroll
    for (int j = 0; j < 8; ++j) r[j] = (s[j] + s[j + 8]) + s[j + 16];
    float res = ((r[0] + r[1]) + (r[2] + r[3])) + ((r[4] + r[5]) + (r[6] + r[7]));
    return sqrtf(res) + 1e-8f;
}

// Monotone float -> u32 (preserves total order for finite floats)
__device__ __forceinline__ u32 ordf(float f)
{
    u32 u = __float_as_uint(f);
    return ((int)u >= 0) ? (u | 0x80000000u) : ~u;
}

// round-to-nearest-even fp32 -> bf16 bits (finite inputs)
__device__ __forceinline__ u16 bf16_rne(float x)
{
    u32 bits = __float_as_uint(x);
    bits += 0x7fffu + ((bits >> 16) & 1u);
    return (u16)(bits >> 16);
}

// ---------------------------------------------------------------------------
// Kernel 0: normalize rows (numpy-exact fp32); write fp32 feats, bf16 hi/lo
// (K-padded to 32), raw flow slice, and the tgt_out output.
// 256 blocks x 64 thr -> covers 256 CUs (latency-bound kernel).
// R15: vectorized stores (f32x4 / short8) — hipcc does not auto-vectorize
// sub-word stores (G13).
// ---------------------------------------------------------------------------
__global__ __launch_bounds__(64) void prep_kernel(
    const float* __restrict__ x_c,     // [8][12][2][2048]
    const int*   __restrict__ flow_p,
    float*       __restrict__ feats,   // [NROWS][24] normalized fp32
    u16*         __restrict__ fhi,     // [NROWS][32] bf16 hi
    u16*         __restrict__ flo,     // [NROWS][32] bf16 lo
    float*       __restrict__ raw,     // [NROWS][12] raw flow slice
    float*       __restrict__ out)
{
    const int t = blockIdx.x * 64 + threadIdx.x;   // global row
    const int b = t >> 11;
    const int n = t & (NPTS - 1);
    const float* xb = x_c + (size_t)b * CCH * NF * NPTS;

    float v[DIM];
    float fn[DIM];
    {
#pragma clang fp contract(off)
        #pragma unroll
        for (int c = 0; c < CCH; ++c)
            #pragma unroll
            for (int f = 0; f < NF; ++f)
                v[f * CCH + c] = xb[(c * NF + f) * NPTS + n];

        const float den = np_norm_den(v);
        #pragma unroll
        for (int d = 0; d < DIM; ++d) fn[d] = v[d] / den;
    }

    // vectorized feats store: 6 x f32x4
    float* fo = feats + (size_t)t * DIM;
    #pragma unroll
    for (int j = 0; j < 6; ++j)
        *(f32x4*)(fo + 4 * j) = *(f32x4*)(fn + 4 * j);

    // build bf16 hi/lo rows in regs, store as 4 x short8 each
    u16 hb[KPAD], lb[KPAD];
    #pragma unroll
    for (int d = 0; d < DIM; ++d) {
        const u16 h = bf16_rne(fn[d]);
        const float hf = __uint_as_float((u32)h << 16);
        hb[d] = h;
        lb[d] = bf16_rne(fn[d] - hf);
    }
    #pragma unroll
    for (int d = DIM; d < KPAD; ++d) { hb[d] = 0; lb[d] = 0; }

    u16* ho = fhi + (size_t)t * KPAD;
    u16* lo = flo + (size_t)t * KPAD;
    #pragma unroll
    for (int j = 0; j < 4; ++j) {
        *(short8*)(ho + 8 * j) = ((const short8*)hb)[j];
        *(short8*)(lo + 8 * j) = ((const short8*)lb)[j];
    }

    const int flow = flow_p[0];
    float rv[CCH];
    #pragma unroll
    for (int c = 0; c < CCH; ++c) {
        rv[c] = flow ? v[CCH + c] : v[c];
        out[TGT_BASE + ((size_t)b * CCH + c) * NPTS + n] = rv[c];
    }
    float* ro = raw + (size_t)t * CCH;
    #pragma unroll
    for (int j = 0; j < 3; ++j)
        *(f32x4*)(ro + 4 * j) = *(f32x4*)(rv + 4 * j);
}

// 4-stage bitonic cleanup, desc (list must be bitonic)
#define CLEANUP_DESC(arr)                                         \
    _Pragma("unroll")                                             \
    for (int j_ = 8; j_ > 0; j_ >>= 1)                            \
        _Pragma("unroll")                                         \
        for (int i_ = 0; i_ < KTOP; ++i_) {                       \
            const int l_ = i_ | j_;                               \
            if (l_ > i_) {                                        \
                const float a_ = arr[i_], c_ = arr[l_];           \
                arr[i_] = fmaxf(a_, c_);                          \
                arr[l_] = fminf(a_, c_);                          \
            }                                                     \
        }

// Split-bf16 approx dot tile: two independent MFMA chains (acc: hi*hi -> lo*hi,
// acc2: hi*lo) + one f32x4 add.  Extra rounding (~6e-8) is negligible vs the
// 8e-4 threshold margin; final output is index-driven via bit-exact rescue.
#define APPROX_TILE(ACC, AHI, ALO, BHI, BLO)                                  \
    f32x4 ACC  = {0.0f, 0.0f, 0.0f, 0.0f};                                    \
    {                                                                         \
        f32x4 acc2_ = {0.0f, 0.0f, 0.0f, 0.0f};                               \
        ACC   = __builtin_amdgcn_mfma_f32_16x16x32_bf16(AHI, BHI, ACC, 0,0,0);\
        acc2_ = __builtin_amdgcn_mfma_f32_16x16x32_bf16(AHI, BLO, acc2_,0,0,0);\
        ACC   = __builtin_amdgcn_mfma_f32_16x16x32_bf16(ALO, BHI, ACC, 0,0,0);\
        _Pragma("unroll")                                                     \
        for (int i_ = 0; i_ < 4; ++i_) ACC[i_] += acc2_[i_];                  \
    }

// ---------------------------------------------------------------------------
// Fused kernel: block = (b, 16-row chunk), 512 thr = 8 waves.
// R15: launch_bounds cap REVERTED (R14's (512,6) forced VGPR=36 -> spills +
// 42% occupancy; regressed fused 40->48 us).  Natural allocation -> 4 blk/CU.
// R15 reduction rework: round-0 merge replaced by direct assignment;
// 8-wave tournament (6 barriers, 3 rounds) replaced by single publish +
// wave-0 in-register merge tree (2 barriers).
// Pass 2 / rescue / rank-select / gather unchanged except float4 rescue loads.
// ---------------------------------------------------------------------------
__global__ __launch_bounds__(512) void fused_topk_kernel(
    const float* __restrict__ feats,
    const u16*   __restrict__ fhi,
    const u16*   __restrict__ flo,
    const float* __restrict__ raw,
    float*       __restrict__ out)
{
    __shared__ union {
        float wval[NWV * 16 * WVS];   // 10 KiB: per-wave C tiles [w][cand16][row WVS]
        float vk[NWV * KTOP * 16];    // 8 KiB: published lists [w][k][row16]
        u64   ckey[RPB * CBS];        // 14.1 KiB: survivors (aliases, disjoint in time)
    } sh;
    __shared__ float thr_s[RPB];
    __shared__ int   cnt[RPB];
    __shared__ int   sel[RPB][KTOP];

    const int tid  = threadIdx.x;
    const int lane = tid & 63;
    const int w    = __builtin_amdgcn_readfirstlane(tid >> 6);  // 0..7
    const int b     = blockIdx.x >> 7;
    const int chunk = blockIdx.x & 127;
    const int rb    = chunk * RPB;           // row base within batch
    const int p     = lane & 15;             // A-row / C-col index
    const int q     = lane >> 4;             // quad

    if (tid < RPB) cnt[tid] = 0;

    // A fragments: 16 rows (one m-tile), hi/lo
    short8 ahi, alo;
    {
        const size_t ae = ((size_t)(b * NPTS + rb + p)) * KPAD + q * 8;
        ahi = *(const short8*)(fhi + ae);
        alo = *(const short8*)(flo + ae);
    }

    float* wv = sh.wval + w * (16 * WVS);    // private C tile [cand][row]

    // gather 16 approx dots for (row p, cands q*4+i over 4 tiles), sort ASC
    auto gather_sorted16 = [&](int ro, float bv[16]) {
        #pragma unroll
        for (int t = 0; t < 4; ++t) {
            const int cb0 = w * 128 + ro * 64 + t * 16;
            const size_t be = ((size_t)(b * NPTS + cb0 + p)) * KPAD + q * 8;
            const short8 bhi = *(const short8*)(fhi + be);
            const short8 blo = *(const short8*)(flo + be);
            APPROX_TILE(acc, ahi, alo, bhi, blo)
            // lane holds cand p, rows q*4+i  ->  store [cand][row]
            *(f32x4*)(wv + p * WVS + q * 4) = acc;
            // read back: this lane takes row p, cands q*4+i (values only)
            #pragma unroll
            for (int i = 0; i < 4; ++i)
                bv[t * 4 + i] = wv[(q * 4 + i) * WVS + p];
        }
        // bitonic sort 16 ASC
        #pragma unroll
        for (int k = 2; k <= 16; k <<= 1)
            #pragma unroll
            for (int j = k >> 1; j > 0; j >>= 1)
                #pragma unroll
                for (int i = 0; i < 16; ++i) {
                    const int l = i | j;
                    if (l > i) {
                        const float a = bv[i], c = bv[l];
                        if ((i & k) == 0) { bv[i] = fminf(a, c); bv[l] = fmaxf(a, c); }
                        else              { bv[i] = fmaxf(a, c); bv[l] = fminf(a, c); }
                    }
                }
    };

    float vlist[KTOP];
    // ---- Pass 1 (subset: wave w scans [w*128, +128) in 2 rounds x 4 tiles) ----
    {
        float bv[16];
        gather_sorted16(0, bv);
        #pragma unroll
        for (int i = 0; i < 16; ++i) vlist[i] = bv[15 - i];   // desc, no merge
        gather_sorted16(1, bv);
        #pragma unroll
        for (int i = 0; i < 16; ++i) vlist[i] = fmaxf(vlist[i], bv[i]);
        CLEANUP_DESC(vlist)
    }

    // ---- intra-wave merges: unify the 4 row-copies (g-quads) ----
    #pragma unroll
    for (int x = 16; x <= 32; x <<= 1) {
        float other[KTOP];
        #pragma unroll
        for (int k = 0; k < KTOP; ++k) other[k] = __shfl_xor(vlist[k], x);
        #pragma unroll
        for (int i = 0; i < KTOP; ++i)
            vlist[i] = fmaxf(vlist[i], other[KTOP - 1 - i]);
        CLEANUP_DESC(vlist)
    }

    __syncthreads();   // pass-1 tiles dead; alias as vk

    // ---- 8-wave combine: publish once, wave 0 merges in-register ----
    if (q == 0) {
        #pragma unroll
        for (int k = 0; k < KTOP; ++k)
            sh.vk[(w * KTOP + k) * 16 + p] = vlist[k];
    }
    __syncthreads();
    if (w == 0) {
        // lane (p,q): merge lists of waves q and q+4 -> fold via shfl
        float la[KTOP], lb[KTOP];
        #pragma unroll
        for (int k = 0; k < KTOP; ++k) {
            la[k] = sh.vk[(q * KTOP + k) * 16 + p];
            lb[k] = sh.vk[((q + 4) * KTOP + k) * 16 + p];
        }
        #pragma unroll
        for (int i = 0; i < KTOP; ++i)
            la[i] = fmaxf(la[i], lb[KTOP - 1 - i]);
        CLEANUP_DESC(la)
        #pragma unroll
        for (int x = 16; x <= 32; x <<= 1) {
            float other[KTOP];
            #pragma unroll
            for (int k = 0; k < KTOP; ++k) other[k] = __shfl_xor(la[k], x);
            #pragma unroll
            for (int i = 0; i < KTOP; ++i)
                la[i] = fmaxf(la[i], other[KTOP - 1 - i]);
            CLEANUP_DESC(la)
        }
        if (q == 0) thr_s[p] = la[KTOP - 1] - 8e-4f;   // lb - margin
    }
    __syncthreads();                          // thr ready; vk dead -> ckey usable

    // per-position thresholds for this lane's C-fragment rows (q*4+i)
    float thrv[4];
    #pragma unroll
    for (int i = 0; i < 4; ++i) thrv[i] = thr_s[q * 4 + i];

    // ---- Pass 2: all 2048 cands (wave w: [w*256,+256)), register compare ----
    {
        size_t be_n = ((size_t)(b * NPTS + w * 256 + p)) * KPAD + q * 8;
        short8 nbhi = *(const short8*)(fhi + be_n);
        short8 nblo = *(const short8*)(flo + be_n);
        for (int t = 0; t < 16; ++t) {
            const int cb0 = w * 256 + t * 16;
            const short8 bhi = nbhi, blo = nblo;
            if (t < 15) {                         // prefetch next tile
                const size_t be = ((size_t)(b * NPTS + cb0 + 16 + p)) * KPAD + q * 8;
                nbhi = *(const short8*)(fhi + be);
                nblo = *(const short8*)(flo + be);
            }
            APPROX_TILE(acc, ahi, alo, bhi, blo)
            #pragma unroll
            for (int i = 0; i < 4; ++i) {
                if (acc[i] >= thrv[i]) {
                    const int r = q * 4 + i;            // row within chunk
                    const int pos = atomicAdd(&cnt[r], 1);
                    if (pos < CBUF)
                        sh.ckey[r * CBS + pos] = (u64)(u32)(cb0 + p);
                }
            }
        }
    }
    __syncthreads();

    // ---- exact rescue: bit-exact fp32 chain on survivors only ----
    {
        const int r = tid & 15;                  // row within chunk
        const float* fr = feats + (size_t)(b * NPTS + rb + r) * DIM;
        float rfn[DIM];
        #pragma unroll
        for (int j = 0; j < 6; ++j)
            *(f32x4*)(rfn + 4 * j) = *(const f32x4*)(fr + 4 * j);
        const int e = (cnt[r] < CBUF) ? cnt[r] : CBUF;
        for (int pos = tid >> 4; pos < e; pos += 32) {
            const int idx = (int)(u32)sh.ckey[r * CBS + pos];
            const float* cp = feats + (size_t)(b * NPTS + idx) * DIM;
            float cv[DIM];
            #pragma unroll
            for (int j = 0; j < 6; ++j)
                *(f32x4*)(cv + 4 * j) = *(const f32x4*)(cp + 4 * j);
            float acc = 0.0f;
            #pragma unroll
            for (int d = 0; d < DIM; ++d)
                acc = __builtin_fmaf(cv[d], rfn[d], acc);   // exact chain
            sh.ckey[r * CBS + pos] = ((u64)ordf(acc) << 32) | (u32)(2047 - idx);
        }
    }
    __syncthreads();

    // ---- parallel rank-select: 32 threads per row ----
    {
        const int L = tid >> 5;                  // 0..15
        const int g = tid & 31;
        const int e = (cnt[L] < CBUF) ? cnt[L] : CBUF;
        const u64* rowbuf = &sh.ckey[L * CBS];
        for (int pos = g; pos < e; pos += 32) {
            const u64 key = rowbuf[pos];
            int rank = 0;
            for (int p2 = 0; p2 < e; ++p2) rank += (rowbuf[p2] > key);
            if (rank < KTOP) sel[L][rank] = 2047 - (int)(key & 0xFFFFFFFFull);
        }
    }
    __syncthreads();

    // ---- gather: sx_c[b, n, k, c] = raw[(b*2048 + sel)*12 + c] ----
    const int rg = b * NPTS + rb;
    for (int e2 = tid; e2 < RPB * KTOP * CCH; e2 += 512) {
        const int L = e2 / (KTOP * CCH);
        const int r = e2 % (KTOP * CCH);
        const int k = r / CCH;
        const int c = r % CCH;
        out[((size_t)(rg + L) * KTOP + k) * CCH + c] =
            raw[((size_t)b * NPTS + sel[L][k]) * CCH + c];
    }
}

// ---------------------------------------------------------------------------
extern "C" void kernel_launch(void* const* d_in, const int* in_sizes, int n_in,
                              void* d_out, int out_size, void* d_ws, size_t ws_size,
                              hipStream_t stream)
{
    const float* x_c    = (const float*)d_in[0];
    const int*   flow_p = (const int*)d_in[1];
    float*       out    = (float*)d_out;

    float* feats = (float*)((char*)d_ws + WS_FEATS);
    float* raw   = (float*)((char*)d_ws + WS_RAW);
    u16*   fhi   = (u16*)  ((char*)d_ws + WS_FHI);
    u16*   flo   = (u16*)  ((char*)d_ws + WS_FLO);

    prep_kernel<<<NROWS / 64, 64, 0, stream>>>(x_c, flow_p, feats, fhi, flo, raw, out);
    fused_topk_kernel<<<BS * 128, 512, 0, stream>>>(feats, fhi, flo, raw, out);
}

// Round 3
// 93.341 us; speedup vs baseline: 1.1332x; 1.1134x over previous
//
#include <hip/hip_runtime.h>
#include <hip/hip_bf16.h>
#include <math.h>

#define BS   8
#define NPTS 2048
#define CCH  12      // channels per flow
#define NF   2       // flow dim
#define DIM  24      // NF*CCH, feats order: d = f*12 + c
#define KPAD 32      // MFMA K (24 + 8 zero pad)
#define KTOP 16
#define NWV  8       // waves per fused block (512 threads)
#define RPB  16      // rows per block (one m-tile)
#define CBUF 144     // survivor slots per row (~45 expected @ margin 1.6e-2, >10 sigma)
#define CBS  145     // padded stride

#define NROWS    (BS * NPTS)
#define TGT_BASE (NROWS * KTOP * CCH)   // 3145728

// hi-only bf16 approx: |approx - exact| <= 2*2^-8 + accum ~ 7.9e-3; margin = 2*eps
#define MARGIN 0.016f

typedef unsigned long long u64;
typedef unsigned int       u32;
typedef unsigned short     u16;
typedef __attribute__((ext_vector_type(8))) short short8;   // bf16x8 MFMA frag
typedef __attribute__((ext_vector_type(4))) float f32x4;

// ws layout (bytes)
#define WS_FEATS 0                                  // fp32 [NROWS][24]
#define WS_RAW   (NROWS * DIM * 4)                  // fp32 [NROWS][12]
#define WS_FHI   (WS_RAW + NROWS * CCH * 4)         // bf16 [NROWS][32]

// Emulate np.linalg.norm(v) + 1e-8 in float32 exactly (numpy pairwise sum, n=24)
__device__ __forceinline__ float np_norm_den(const float* __restrict__ v)
{
#pragma clang fp contract(off)
    float s[DIM];
    #pragma unroll
    for (int d = 0; d < DIM; ++d) s[d] = v[d] * v[d];
    float r[8];
    #pragma unroll
    for (int j = 0; j < 8; ++j) r[j] = (s[j] + s[j + 8]) + s[j + 16];
    float res = ((r[0] + r[1]) + (r[2] + r[3])) + ((r[4] + r[5]) + (r[6] + r[7]));
    return sqrtf(res) + 1e-8f;
}

// Monotone float -> u32 (preserves total order for finite floats)
__device__ __forceinline__ u32 ordf(float f)
{
    u32 u = __float_as_uint(f);
    return ((int)u >= 0) ? (u | 0x80000000u) : ~u;
}

// round-to-nearest-even fp32 -> bf16 bits (finite inputs)
__device__ __forceinline__ u16 bf16_rne(float x)
{
    u32 bits = __float_as_uint(x);
    bits += 0x7fffu + ((bits >> 16) & 1u);
    return (u16)(bits >> 16);
}

// running top-4 insert (desc t0>=t1>=t2>=t3): 1 max + 3 med3 (or min/max fallback)
__device__ __forceinline__ void ins4(float& t0, float& t1, float& t2, float& t3, float v)
{
#if __has_builtin(__builtin_amdgcn_fmed3f)
    const float n0 = fmaxf(t0, v);
    const float n1 = __builtin_amdgcn_fmed3f(t0, t1, v);
    const float n2 = __builtin_amdgcn_fmed3f(t1, t2, v);
    const float n3 = __builtin_amdgcn_fmed3f(t2, t3, v);
#else
    const float n0 = fmaxf(t0, v);
    const float n1 = fmaxf(t1, fminf(t0, v));
    const float n2 = fmaxf(t2, fminf(t1, v));
    const float n3 = fmaxf(t3, fminf(t2, v));
#endif
    t0 = n0; t1 = n1; t2 = n2; t3 = n3;
}

#define CE(a, b) { const float h_ = fmaxf(a, b), l_ = fminf(a, b); a = h_; b = l_; }

// ---------------------------------------------------------------------------
// Kernel 0: normalize rows (numpy-exact fp32); write fp32 feats, bf16 hi
// (K-padded to 32), raw flow slice, and the tgt_out output.
// 256 blocks x 64 thr -> covers 256 CUs (latency-bound kernel).
// R16: lo-split dropped (fused is hi-only now) -> no flo buffer/compute.
// ---------------------------------------------------------------------------
__global__ __launch_bounds__(64) void prep_kernel(
    const float* __restrict__ x_c,     // [8][12][2][2048]
    const int*   __restrict__ flow_p,
    float*       __restrict__ feats,   // [NROWS][24] normalized fp32
    u16*         __restrict__ fhi,     // [NROWS][32] bf16 hi
    float*       __restrict__ raw,     // [NROWS][12] raw flow slice
    float*       __restrict__ out)
{
    const int t = blockIdx.x * 64 + threadIdx.x;   // global row
    const int b = t >> 11;
    const int n = t & (NPTS - 1);
    const float* xb = x_c + (size_t)b * CCH * NF * NPTS;

    float v[DIM];
    float fn[DIM];
    {
#pragma clang fp contract(off)
        #pragma unroll
        for (int c = 0; c < CCH; ++c)
            #pragma unroll
            for (int f = 0; f < NF; ++f)
                v[f * CCH + c] = xb[(c * NF + f) * NPTS + n];

        const float den = np_norm_den(v);
        #pragma unroll
        for (int d = 0; d < DIM; ++d) fn[d] = v[d] / den;
    }

    // vectorized feats store: 6 x f32x4
    float* fo = feats + (size_t)t * DIM;
    #pragma unroll
    for (int j = 0; j < 6; ++j)
        *(f32x4*)(fo + 4 * j) = *(f32x4*)(fn + 4 * j);

    // bf16 hi row in regs, store as 4 x short8
    u16 hb[KPAD];
    #pragma unroll
    for (int d = 0; d < DIM; ++d) hb[d] = bf16_rne(fn[d]);
    #pragma unroll
    for (int d = DIM; d < KPAD; ++d) hb[d] = 0;

    u16* ho = fhi + (size_t)t * KPAD;
    #pragma unroll
    for (int j = 0; j < 4; ++j)
        *(short8*)(ho + 8 * j) = ((const short8*)hb)[j];

    const int flow = flow_p[0];
    float rv[CCH];
    #pragma unroll
    for (int c = 0; c < CCH; ++c) {
        rv[c] = flow ? v[CCH + c] : v[c];
        out[TGT_BASE + ((size_t)b * CCH + c) * NPTS + n] = rv[c];
    }
    float* ro = raw + (size_t)t * CCH;
    #pragma unroll
    for (int j = 0; j < 3; ++j)
        *(f32x4*)(ro + 4 * j) = *(f32x4*)(rv + 4 * j);
}

// ---------------------------------------------------------------------------
// Fused kernel: block = (b, 16-row chunk), 512 thr = 8 waves, 1024 blocks
// (4 blocks/CU, wave-capped).
// R16 restructure:
//  * SWAPPED MFMA operands: acc = mfma(cand_frag, row_frag).  C/D layout
//    (col=lane&15 -> B-col = our ROW, row=(lane>>4)*4+i -> A-row = cand)
//    makes every value lane-local to its row: the pass-1 LDS transpose is
//    gone.  Per-lane load addresses are identical to the unswapped version.
//  * hi-only MFMA (1 per tile, was 3): eps 7.9e-3, margin 1.6e-2, CBUF 144.
//  * Pass-1 top-16-of-subset replaced by top-4/wave collection (running
//    insert, 2 interleaved lists for ILP) + q-merges; wave 0 computes the
//    exact 16th of the 32 collected values (valid lower bound of the full
//    16th since collected subset-of-subset; only tightness varies).
// Pass 2: all 2048 cands, compare vs thr in C-frag registers, sparse append.
// Exact rescue (bit-exact fp32 chain) + parallel rank-select + gather.
// ---------------------------------------------------------------------------
__global__ __launch_bounds__(512) void fused_topk_kernel(
    const float* __restrict__ feats,
    const u16*   __restrict__ fhi,
    const float* __restrict__ raw,
    float*       __restrict__ out)
{
    __shared__ union {
        f32x4 vk4[NWV * 16];          // 2 KiB: per-wave top-4 lists [w][row16]
        u64   ckey[RPB * CBS];        // 18.1 KiB: survivors (disjoint in time)
    } sh;
    __shared__ float thr_s[RPB];
    __shared__ int   cnt[RPB];
    __shared__ int   sel[RPB][KTOP];

    const int tid  = threadIdx.x;
    const int lane = tid & 63;
    const int w    = __builtin_amdgcn_readfirstlane(tid >> 6);  // 0..7
    const int b     = blockIdx.x >> 7;
    const int chunk = blockIdx.x & 127;
    const int rb    = chunk * RPB;           // row base within batch
    const int p     = lane & 15;             // our row (C-col with swapped ops)
    const int q     = lane >> 4;             // cand quad (C-row group)

    if (tid < RPB) cnt[tid] = 0;

    // row fragment (B-operand under swap): rows rb+p, k = q*8..q*8+7
    short8 arow;
    {
        const size_t ae = ((size_t)(b * NPTS + rb + p)) * KPAD + q * 8;
        arow = *(const short8*)(fhi + ae);
    }

    // ---- Pass 1: wave w scans cands [w*128, +128) (8 tiles), running top-4
    //      per (row p, cand-slice q); 2 interleaved lists halve the dep chain.
    float ta0 = -3.0f, ta1 = -3.0f, ta2 = -3.0f, ta3 = -3.0f;
    float tb0 = -3.0f, tb1 = -3.0f, tb2 = -3.0f, tb3 = -3.0f;
    {
        size_t be_n = ((size_t)(b * NPTS + w * 128 + p)) * KPAD + q * 8;
        short8 nb = *(const short8*)(fhi + be_n);
        #pragma unroll
        for (int t = 0; t < 8; ++t) {
            const short8 bh = nb;
            if (t < 7) {
                const size_t be = ((size_t)(b * NPTS + w * 128 + (t + 1) * 16 + p)) * KPAD + q * 8;
                nb = *(const short8*)(fhi + be);
            }
            f32x4 acc = {0.0f, 0.0f, 0.0f, 0.0f};
            acc = __builtin_amdgcn_mfma_f32_16x16x32_bf16(bh, arow, acc, 0, 0, 0);
            if (t & 1) {
                #pragma unroll
                for (int i = 0; i < 4; ++i) ins4(tb0, tb1, tb2, tb3, acc[i]);
            } else {
                #pragma unroll
                for (int i = 0; i < 4; ++i) ins4(ta0, ta1, ta2, ta3, acc[i]);
            }
        }
    }
    // merge the two interleaved lists -> top-4 (bitonic: max(a_i, b_{3-i}) + cleanup)
    float t0 = fmaxf(ta0, tb3), t1 = fmaxf(ta1, tb2), t2 = fmaxf(ta2, tb1), t3 = fmaxf(ta3, tb0);
    CE(t0, t2) CE(t1, t3) CE(t0, t1) CE(t2, t3)

    // ---- unify the 4 q-copies of each row (shfl merges) ----
    #pragma unroll
    for (int x = 16; x <= 32; x <<= 1) {
        const float o0 = __shfl_xor(t0, x), o1 = __shfl_xor(t1, x);
        const float o2 = __shfl_xor(t2, x), o3 = __shfl_xor(t3, x);
        float m0 = fmaxf(t0, o3), m1 = fmaxf(t1, o2), m2 = fmaxf(t2, o1), m3 = fmaxf(t3, o0);
        CE(m0, m2) CE(m1, m3) CE(m0, m1) CE(m2, m3)
        t0 = m0; t1 = m1; t2 = m2; t3 = m3;
    }

    // ---- publish per-wave top-4 per row ----
    if (q == 0) {
        f32x4 v4 = {t0, t1, t2, t3};
        sh.vk4[w * 16 + p] = v4;
    }
    __syncthreads();

    // ---- wave 0: exact 16th of the 32 collected values per row ----
    if (w == 0) {
        const int j = q;                       // 0..3
        const f32x4 A  = sh.vk4[j * 16 + p];
        const f32x4 Bv = sh.vk4[(j + 4) * 16 + p];
        // merge two sorted-4 desc -> sorted-8 desc
        float s0 = fmaxf(A[0], Bv[3]), s1 = fmaxf(A[1], Bv[2]);
        float s2 = fmaxf(A[2], Bv[1]), s3 = fmaxf(A[3], Bv[0]);
        float s4 = fminf(A[0], Bv[3]), s5 = fminf(A[1], Bv[2]);
        float s6 = fminf(A[2], Bv[1]), s7 = fminf(A[3], Bv[0]);
        CE(s0, s2) CE(s1, s3) CE(s0, s1) CE(s2, s3)
        CE(s4, s6) CE(s5, s7) CE(s4, s5) CE(s6, s7)
        float s[8] = {s0, s1, s2, s3, s4, s5, s6, s7};
        // j ^ 1 merge: two sorted-8 -> sorted-16 desc
        float t16[16];
        {
            float o[8];
            #pragma unroll
            for (int i = 0; i < 8; ++i) o[i] = __shfl_xor(s[i], 16);
            #pragma unroll
            for (int i = 0; i < 8; ++i) {
                t16[i]     = fmaxf(s[i], o[7 - i]);
                t16[8 + i] = fminf(s[i], o[7 - i]);
            }
            #pragma unroll
            for (int base = 0; base < 16; base += 8) {
                CE(t16[base + 0], t16[base + 4]) CE(t16[base + 1], t16[base + 5])
                CE(t16[base + 2], t16[base + 6]) CE(t16[base + 3], t16[base + 7])
                CE(t16[base + 0], t16[base + 2]) CE(t16[base + 1], t16[base + 3])
                CE(t16[base + 4], t16[base + 6]) CE(t16[base + 5], t16[base + 7])
                CE(t16[base + 0], t16[base + 1]) CE(t16[base + 2], t16[base + 3])
                CE(t16[base + 4], t16[base + 5]) CE(t16[base + 6], t16[base + 7])
            }
        }
        // j ^ 2 final: 16th of union = min_i max(mine[i], other[15-i])
        float z[16];
        #pragma unroll
        for (int i = 0; i < 16; ++i)
            z[i] = fmaxf(t16[i], __shfl_xor(t16[15 - i], 32));
        float mn = z[0];
        #pragma unroll
        for (int i = 1; i < 16; ++i) mn = fminf(mn, z[i]);
        if (q == 0) thr_s[p] = mn - MARGIN;    // lb - 2*eps
    }
    __syncthreads();                 // thr ready; vk4 dead -> ckey usable

    const float thrp = thr_s[p];     // this lane's row threshold

    // ---- Pass 2: all 2048 cands (wave w: [w*256,+256)), register compare ----
    {
        size_t be_n = ((size_t)(b * NPTS + w * 256 + p)) * KPAD + q * 8;
        short8 nb = *(const short8*)(fhi + be_n);
        for (int t = 0; t < 16; ++t) {
            const int cb0 = w * 256 + t * 16;
            const short8 bh = nb;
            if (t < 15) {                         // prefetch next tile
                const size_t be = ((size_t)(b * NPTS + cb0 + 16 + p)) * KPAD + q * 8;
                nb = *(const short8*)(fhi + be);
            }
            f32x4 acc = {0.0f, 0.0f, 0.0f, 0.0f};
            acc = __builtin_amdgcn_mfma_f32_16x16x32_bf16(bh, arow, acc, 0, 0, 0);
            #pragma unroll
            for (int i = 0; i < 4; ++i) {
                if (acc[i] >= thrp) {
                    const int pos = atomicAdd(&cnt[p], 1);
                    if (pos < CBUF)
                        sh.ckey[p * CBS + pos] = (u64)(u32)(cb0 + q * 4 + i);
                }
            }
        }
    }
    __syncthreads();

    // ---- exact rescue: bit-exact fp32 chain on survivors only ----
    {
        const int r = tid & 15;                  // row within chunk
        const float* fr = feats + (size_t)(b * NPTS + rb + r) * DIM;
        float rfn[DIM];
        #pragma unroll
        for (int j = 0; j < 6; ++j)
            *(f32x4*)(rfn + 4 * j) = *(const f32x4*)(fr + 4 * j);
        const int e = (cnt[r] < CBUF) ? cnt[r] : CBUF;
        for (int pos = tid >> 4; pos < e; pos += 32) {
            const int idx = (int)(u32)sh.ckey[r * CBS + pos];
            const float* cp = feats + (size_t)(b * NPTS + idx) * DIM;
            float cv[DIM];
            #pragma unroll
            for (int j = 0; j < 6; ++j)
                *(f32x4*)(cv + 4 * j) = *(const f32x4*)(cp + 4 * j);
            float acc = 0.0f;
            #pragma unroll
            for (int d = 0; d < DIM; ++d)
                acc = __builtin_fmaf(cv[d], rfn[d], acc);   // exact chain
            sh.ckey[r * CBS + pos] = ((u64)ordf(acc) << 32) | (u32)(2047 - idx);
        }
    }
    __syncthreads();

    // ---- parallel rank-select: 32 threads per row ----
    {
        const int L = tid >> 5;                  // 0..15
        const int g = tid & 31;
        const int e = (cnt[L] < CBUF) ? cnt[L] : CBUF;
        const u64* rowbuf = &sh.ckey[L * CBS];
        for (int pos = g; pos < e; pos += 32) {
            const u64 key = rowbuf[pos];
            int rank = 0;
            for (int p2 = 0; p2 < e; ++p2) rank += (rowbuf[p2] > key);
            if (rank < KTOP) sel[L][rank] = 2047 - (int)(key & 0xFFFFFFFFull);
        }
    }
    __syncthreads();

    // ---- gather: sx_c[b, n, k, c] = raw[(b*2048 + sel)*12 + c] ----
    const int rg = b * NPTS + rb;
    for (int e2 = tid; e2 < RPB * KTOP * CCH; e2 += 512) {
        const int L = e2 / (KTOP * CCH);
        const int r = e2 % (KTOP * CCH);
        const int k = r / CCH;
        const int c = r % CCH;
        out[((size_t)(rg + L) * KTOP + k) * CCH + c] =
            raw[((size_t)b * NPTS + sel[L][k]) * CCH + c];
    }
}

// ---------------------------------------------------------------------------
extern "C" void kernel_launch(void* const* d_in, const int* in_sizes, int n_in,
                              void* d_out, int out_size, void* d_ws, size_t ws_size,
                              hipStream_t stream)
{
    const float* x_c    = (const float*)d_in[0];
    const int*   flow_p = (const int*)d_in[1];
    float*       out    = (float*)d_out;

    float* feats = (float*)((char*)d_ws + WS_FEATS);
    float* raw   = (float*)((char*)d_ws + WS_RAW);
    u16*   fhi   = (u16*)  ((char*)d_ws + WS_FHI);

    prep_kernel<<<NROWS / 64, 64, 0, stream>>>(x_c, flow_p, feats, fhi, raw, out);
    fused_topk_kernel<<<BS * 128, 512, 0, stream>>>(feats, fhi, raw, out);
}

// Round 4
// 93.063 us; speedup vs baseline: 1.1366x; 1.0030x over previous
//
#include <hip/hip_runtime.h>
#include <hip/hip_bf16.h>
#include <math.h>

#define BS   8
#define NPTS 2048
#define CCH  12      // channels per flow
#define NF   2       // flow dim
#define DIM  24      // NF*CCH, feats order: d = f*12 + c
#define KPAD 32      // MFMA K (24 + 8 zero pad)
#define KTOP 16
#define NWV  8       // waves per fused block (512 threads)
#define RPB  16      // rows per block (one m-tile)
#define CBUF 144     // survivor slots per row (~45 expected @ margin 1.6e-2, >10 sigma)
#define CBS  145     // padded stride

#define NROWS    (BS * NPTS)
#define TGT_BASE (NROWS * KTOP * CCH)   // 3145728

// hi-only bf16 approx: |approx - exact| <= 2*2^-8 + accum ~ 7.9e-3; margin = 2*eps
#define MARGIN 0.016f

typedef unsigned long long u64;
typedef unsigned int       u32;
typedef unsigned short     u16;
typedef __attribute__((ext_vector_type(8))) short short8;   // bf16x8 MFMA frag
typedef __attribute__((ext_vector_type(4))) float f32x4;

// ws layout (bytes)
#define WS_FEATS 0                                  // fp32 [NROWS][24]
#define WS_RAW   (NROWS * DIM * 4)                  // fp32 [NROWS][12]
#define WS_FHI   (WS_RAW + NROWS * CCH * 4)         // bf16 [NROWS][32]

// Emulate np.linalg.norm(v) + 1e-8 in float32 exactly (numpy pairwise sum, n=24)
__device__ __forceinline__ float np_norm_den(const float* __restrict__ v)
{
#pragma clang fp contract(off)
    float s[DIM];
    #pragma unroll
    for (int d = 0; d < DIM; ++d) s[d] = v[d] * v[d];
    float r[8];
    #pragma unroll
    for (int j = 0; j < 8; ++j) r[j] = (s[j] + s[j + 8]) + s[j + 16];
    float res = ((r[0] + r[1]) + (r[2] + r[3])) + ((r[4] + r[5]) + (r[6] + r[7]));
    return sqrtf(res) + 1e-8f;
}

// Monotone float -> u32 (preserves total order for finite floats)
__device__ __forceinline__ u32 ordf(float f)
{
    u32 u = __float_as_uint(f);
    return ((int)u >= 0) ? (u | 0x80000000u) : ~u;
}

// round-to-nearest-even fp32 -> bf16 bits (finite inputs)
__device__ __forceinline__ u16 bf16_rne(float x)
{
    u32 bits = __float_as_uint(x);
    bits += 0x7fffu + ((bits >> 16) & 1u);
    return (u16)(bits >> 16);
}

// running top-4 insert (desc t0>=t1>=t2>=t3): 1 max + 3 med3
__device__ __forceinline__ void ins4(float& t0, float& t1, float& t2, float& t3, float v)
{
#if __has_builtin(__builtin_amdgcn_fmed3f)
    const float n0 = fmaxf(t0, v);
    const float n1 = __builtin_amdgcn_fmed3f(t0, t1, v);
    const float n2 = __builtin_amdgcn_fmed3f(t1, t2, v);
    const float n3 = __builtin_amdgcn_fmed3f(t2, t3, v);
#else
    const float n0 = fmaxf(t0, v);
    const float n1 = fmaxf(t1, fminf(t0, v));
    const float n2 = fmaxf(t2, fminf(t1, v));
    const float n3 = fmaxf(t3, fminf(t2, v));
#endif
    t0 = n0; t1 = n1; t2 = n2; t3 = n3;
}

#define CE(a, b) { const float h_ = fmaxf(a, b), l_ = fminf(a, b); a = h_; b = l_; }

// ---------------------------------------------------------------------------
// Kernel 0: normalize rows (numpy-exact fp32); write fp32 feats, bf16 hi
// (K-padded to 32), raw flow slice, and the tgt_out output.
// 256 blocks x 64 thr -> covers 256 CUs (latency-bound kernel).
// ---------------------------------------------------------------------------
__global__ __launch_bounds__(64) void prep_kernel(
    const float* __restrict__ x_c,     // [8][12][2][2048]
    const int*   __restrict__ flow_p,
    float*       __restrict__ feats,   // [NROWS][24] normalized fp32
    u16*         __restrict__ fhi,     // [NROWS][32] bf16 hi
    float*       __restrict__ raw,     // [NROWS][12] raw flow slice
    float*       __restrict__ out)
{
    const int t = blockIdx.x * 64 + threadIdx.x;   // global row
    const int b = t >> 11;
    const int n = t & (NPTS - 1);
    const float* xb = x_c + (size_t)b * CCH * NF * NPTS;

    float v[DIM];
    float fn[DIM];
    {
#pragma clang fp contract(off)
        #pragma unroll
        for (int c = 0; c < CCH; ++c)
            #pragma unroll
            for (int f = 0; f < NF; ++f)
                v[f * CCH + c] = xb[(c * NF + f) * NPTS + n];

        const float den = np_norm_den(v);
        #pragma unroll
        for (int d = 0; d < DIM; ++d) fn[d] = v[d] / den;
    }

    // vectorized feats store: 6 x f32x4
    float* fo = feats + (size_t)t * DIM;
    #pragma unroll
    for (int j = 0; j < 6; ++j)
        *(f32x4*)(fo + 4 * j) = *(f32x4*)(fn + 4 * j);

    // bf16 hi row in regs, store as 4 x short8
    u16 hb[KPAD];
    #pragma unroll
    for (int d = 0; d < DIM; ++d) hb[d] = bf16_rne(fn[d]);
    #pragma unroll
    for (int d = DIM; d < KPAD; ++d) hb[d] = 0;

    u16* ho = fhi + (size_t)t * KPAD;
    #pragma unroll
    for (int j = 0; j < 4; ++j)
        *(short8*)(ho + 8 * j) = ((const short8*)hb)[j];

    const int flow = flow_p[0];
    float rv[CCH];
    #pragma unroll
    for (int c = 0; c < CCH; ++c) {
        rv[c] = flow ? v[CCH + c] : v[c];
        out[TGT_BASE + ((size_t)b * CCH + c) * NPTS + n] = rv[c];
    }
    float* ro = raw + (size_t)t * CCH;
    #pragma unroll
    for (int j = 0; j < 3; ++j)
        *(f32x4*)(ro + 4 * j) = *(f32x4*)(rv + 4 * j);
}

// ---------------------------------------------------------------------------
// Fused kernel: block = (b, 16-row chunk), 512 thr = 8 waves, 1024 blocks.
// R16: swapped MFMA operands (row lane-local, no LDS transpose); hi-only
// MFMA; top-4/wave collection + exact 16th-of-32 threshold.
// R17: u32 incremental tile offsets (kill 64-bit addr chains) + depth-2
// prefetch with named A/B buffers (static indexing, rule #20) in both scans.
// Pass 2: all 2048 cands, compare vs thr in C-frag registers, sparse append.
// Exact rescue (bit-exact fp32 chain) + parallel rank-select + gather.
// ---------------------------------------------------------------------------
__global__ __launch_bounds__(512) void fused_topk_kernel(
    const float* __restrict__ feats,
    const u16*   __restrict__ fhi,
    const float* __restrict__ raw,
    float*       __restrict__ out)
{
    __shared__ union {
        f32x4 vk4[NWV * 16];          // 2 KiB: per-wave top-4 lists [w][row16]
        u64   ckey[RPB * CBS];        // 18.1 KiB: survivors (disjoint in time)
    } sh;
    __shared__ float thr_s[RPB];
    __shared__ int   cnt[RPB];
    __shared__ int   sel[RPB][KTOP];

    const int tid  = threadIdx.x;
    const int lane = tid & 63;
    const int w    = __builtin_amdgcn_readfirstlane(tid >> 6);  // 0..7
    const int b     = blockIdx.x >> 7;
    const int chunk = blockIdx.x & 127;
    const int rb    = chunk * RPB;           // row base within batch
    const int p     = lane & 15;             // our row (C-col with swapped ops)
    const int q     = lane >> 4;             // cand quad (C-row group)

    if (tid < RPB) cnt[tid] = 0;

    // row fragment (B-operand under swap): rows rb+p, k = q*8..q*8+7
    short8 arow;
    {
        const u32 ae = (u32)((b * NPTS + rb + p) * KPAD + q * 8);
        arow = *(const short8*)(fhi + ae);
    }

    // ---- Pass 1: wave w scans cands [w*128, +128) (8 tiles), running top-4
    //      per (row p, cand-slice q); 2 interleaved lists + depth-2 prefetch.
    float ta0 = -3.0f, ta1 = -3.0f, ta2 = -3.0f, ta3 = -3.0f;
    float tb0 = -3.0f, tb1 = -3.0f, tb2 = -3.0f, tb3 = -3.0f;
    {
        const u32 base1 = (u32)((b * NPTS + w * 128 + p) * KPAD + q * 8);
        short8 pA = *(const short8*)(fhi + base1);          // tile t
        short8 pB = *(const short8*)(fhi + base1 + 512);    // tile t+1
        #pragma unroll
        for (int t = 0; t < 8; t += 2) {
            const short8 c0 = pA;
            if (t + 2 < 8) pA = *(const short8*)(fhi + base1 + (u32)(t + 2) * 512);
            f32x4 acc0 = {0.0f, 0.0f, 0.0f, 0.0f};
            acc0 = __builtin_amdgcn_mfma_f32_16x16x32_bf16(c0, arow, acc0, 0, 0, 0);
            const short8 c1 = pB;
            if (t + 3 < 8) pB = *(const short8*)(fhi + base1 + (u32)(t + 3) * 512);
            f32x4 acc1 = {0.0f, 0.0f, 0.0f, 0.0f};
            acc1 = __builtin_amdgcn_mfma_f32_16x16x32_bf16(c1, arow, acc1, 0, 0, 0);
            #pragma unroll
            for (int i = 0; i < 4; ++i) ins4(ta0, ta1, ta2, ta3, acc0[i]);
            #pragma unroll
            for (int i = 0; i < 4; ++i) ins4(tb0, tb1, tb2, tb3, acc1[i]);
        }
    }
    // merge the two interleaved lists -> top-4 (bitonic: max(a_i, b_{3-i}) + cleanup)
    float t0 = fmaxf(ta0, tb3), t1 = fmaxf(ta1, tb2), t2 = fmaxf(ta2, tb1), t3 = fmaxf(ta3, tb0);
    CE(t0, t2) CE(t1, t3) CE(t0, t1) CE(t2, t3)

    // ---- unify the 4 q-copies of each row (shfl merges) ----
    #pragma unroll
    for (int x = 16; x <= 32; x <<= 1) {
        const float o0 = __shfl_xor(t0, x), o1 = __shfl_xor(t1, x);
        const float o2 = __shfl_xor(t2, x), o3 = __shfl_xor(t3, x);
        float m0 = fmaxf(t0, o3), m1 = fmaxf(t1, o2), m2 = fmaxf(t2, o1), m3 = fmaxf(t3, o0);
        CE(m0, m2) CE(m1, m3) CE(m0, m1) CE(m2, m3)
        t0 = m0; t1 = m1; t2 = m2; t3 = m3;
    }

    // ---- publish per-wave top-4 per row ----
    if (q == 0) {
        f32x4 v4 = {t0, t1, t2, t3};
        sh.vk4[w * 16 + p] = v4;
    }
    __syncthreads();

    // ---- wave 0: exact 16th of the 32 collected values per row ----
    if (w == 0) {
        const int j = q;                       // 0..3
        const f32x4 A  = sh.vk4[j * 16 + p];
        const f32x4 Bv = sh.vk4[(j + 4) * 16 + p];
        // merge two sorted-4 desc -> sorted-8 desc
        float s0 = fmaxf(A[0], Bv[3]), s1 = fmaxf(A[1], Bv[2]);
        float s2 = fmaxf(A[2], Bv[1]), s3 = fmaxf(A[3], Bv[0]);
        float s4 = fminf(A[0], Bv[3]), s5 = fminf(A[1], Bv[2]);
        float s6 = fminf(A[2], Bv[1]), s7 = fminf(A[3], Bv[0]);
        CE(s0, s2) CE(s1, s3) CE(s0, s1) CE(s2, s3)
        CE(s4, s6) CE(s5, s7) CE(s4, s5) CE(s6, s7)
        float s[8] = {s0, s1, s2, s3, s4, s5, s6, s7};
        // j ^ 1 merge: two sorted-8 -> sorted-16 desc
        float t16[16];
        {
            float o[8];
            #pragma unroll
            for (int i = 0; i < 8; ++i) o[i] = __shfl_xor(s[i], 16);
            #pragma unroll
            for (int i = 0; i < 8; ++i) {
                t16[i]     = fmaxf(s[i], o[7 - i]);
                t16[8 + i] = fminf(s[i], o[7 - i]);
            }
            #pragma unroll
            for (int base = 0; base < 16; base += 8) {
                CE(t16[base + 0], t16[base + 4]) CE(t16[base + 1], t16[base + 5])
                CE(t16[base + 2], t16[base + 6]) CE(t16[base + 3], t16[base + 7])
                CE(t16[base + 0], t16[base + 2]) CE(t16[base + 1], t16[base + 3])
                CE(t16[base + 4], t16[base + 6]) CE(t16[base + 5], t16[base + 7])
                CE(t16[base + 0], t16[base + 1]) CE(t16[base + 2], t16[base + 3])
                CE(t16[base + 4], t16[base + 5]) CE(t16[base + 6], t16[base + 7])
            }
        }
        // j ^ 2 final: 16th of union = min_i max(mine[i], other[15-i])
        float z[16];
        #pragma unroll
        for (int i = 0; i < 16; ++i)
            z[i] = fmaxf(t16[i], __shfl_xor(t16[15 - i], 32));
        float mn = z[0];
        #pragma unroll
        for (int i = 1; i < 16; ++i) mn = fminf(mn, z[i]);
        if (q == 0) thr_s[p] = mn - MARGIN;    // lb - 2*eps
    }
    __syncthreads();                 // thr ready; vk4 dead -> ckey usable

    const float thrp = thr_s[p];     // this lane's row threshold

    // ---- Pass 2: all 2048 cands (wave w: [w*256,+256)), depth-2 prefetch ----
    {
        const u32 base2 = (u32)((b * NPTS + w * 256 + p) * KPAD + q * 8);
        short8 pA = *(const short8*)(fhi + base2);
        short8 pB = *(const short8*)(fhi + base2 + 512);
        #pragma unroll
        for (int t = 0; t < 16; t += 2) {
            const short8 c0 = pA;
            if (t + 2 < 16) pA = *(const short8*)(fhi + base2 + (u32)(t + 2) * 512);
            f32x4 acc0 = {0.0f, 0.0f, 0.0f, 0.0f};
            acc0 = __builtin_amdgcn_mfma_f32_16x16x32_bf16(c0, arow, acc0, 0, 0, 0);
            const short8 c1 = pB;
            if (t + 3 < 16) pB = *(const short8*)(fhi + base2 + (u32)(t + 3) * 512);
            f32x4 acc1 = {0.0f, 0.0f, 0.0f, 0.0f};
            acc1 = __builtin_amdgcn_mfma_f32_16x16x32_bf16(c1, arow, acc1, 0, 0, 0);
            const int cb0 = w * 256 + t * 16;
            #pragma unroll
            for (int i = 0; i < 4; ++i) {
                if (acc0[i] >= thrp) {
                    const int pos = atomicAdd(&cnt[p], 1);
                    if (pos < CBUF)
                        sh.ckey[p * CBS + pos] = (u64)(u32)(cb0 + q * 4 + i);
                }
            }
            #pragma unroll
            for (int i = 0; i < 4; ++i) {
                if (acc1[i] >= thrp) {
                    const int pos = atomicAdd(&cnt[p], 1);
                    if (pos < CBUF)
                        sh.ckey[p * CBS + pos] = (u64)(u32)(cb0 + 16 + q * 4 + i);
                }
            }
        }
    }
    __syncthreads();

    // ---- exact rescue: bit-exact fp32 chain on survivors only ----
    {
        const int r = tid & 15;                  // row within chunk
        const float* fr = feats + (u32)((b * NPTS + rb + r) * DIM);
        float rfn[DIM];
        #pragma unroll
        for (int j = 0; j < 6; ++j)
            *(f32x4*)(rfn + 4 * j) = *(const f32x4*)(fr + 4 * j);
        const int e = (cnt[r] < CBUF) ? cnt[r] : CBUF;
        for (int pos = tid >> 4; pos < e; pos += 32) {
            const int idx = (int)(u32)sh.ckey[r * CBS + pos];
            const float* cp = feats + (u32)((b * NPTS + idx) * DIM);
            float cv[DIM];
            #pragma unroll
            for (int j = 0; j < 6; ++j)
                *(f32x4*)(cv + 4 * j) = *(const f32x4*)(cp + 4 * j);
            float acc = 0.0f;
            #pragma unroll
            for (int d = 0; d < DIM; ++d)
                acc = __builtin_fmaf(cv[d], rfn[d], acc);   // exact chain
            sh.ckey[r * CBS + pos] = ((u64)ordf(acc) << 32) | (u32)(2047 - idx);
        }
    }
    __syncthreads();

    // ---- parallel rank-select: 32 threads per row ----
    {
        const int L = tid >> 5;                  // 0..15
        const int g = tid & 31;
        const int e = (cnt[L] < CBUF) ? cnt[L] : CBUF;
        const u64* rowbuf = &sh.ckey[L * CBS];
        for (int pos = g; pos < e; pos += 32) {
            const u64 key = rowbuf[pos];
            int rank = 0;
            for (int p2 = 0; p2 < e; ++p2) rank += (rowbuf[p2] > key);
            if (rank < KTOP) sel[L][rank] = 2047 - (int)(key & 0xFFFFFFFFull);
        }
    }
    __syncthreads();

    // ---- gather: sx_c[b, n, k, c] = raw[(b*2048 + sel)*12 + c] ----
    const int rg = b * NPTS + rb;
    for (int e2 = tid; e2 < RPB * KTOP * CCH; e2 += 512) {
        const int L = e2 / (KTOP * CCH);
        const int r = e2 % (KTOP * CCH);
        const int k = r / CCH;
        const int c = r % CCH;
        out[((size_t)(rg + L) * KTOP + k) * CCH + c] =
            raw[(u32)((b * NPTS + sel[L][k]) * CCH) + c];
    }
}

// ---------------------------------------------------------------------------
extern "C" void kernel_launch(void* const* d_in, const int* in_sizes, int n_in,
                              void* d_out, int out_size, void* d_ws, size_t ws_size,
                              hipStream_t stream)
{
    const float* x_c    = (const float*)d_in[0];
    const int*   flow_p = (const int*)d_in[1];
    float*       out    = (float*)d_out;

    float* feats = (float*)((char*)d_ws + WS_FEATS);
    float* raw   = (float*)((char*)d_ws + WS_RAW);
    u16*   fhi   = (u16*)  ((char*)d_ws + WS_FHI);

    prep_kernel<<<NROWS / 64, 64, 0, stream>>>(x_c, flow_p, feats, fhi, raw, out);
    fused_topk_kernel<<<BS * 128, 512, 0, stream>>>(feats, fhi, raw, out);
}